// Round 2
// baseline (322.591 us; speedup 1.0000x reference)
//
#include <hip/hip_runtime.h>

// Water constraint residuals:
//   x: [B=16, N=200000, D=18] fp32; positions = x[..., :9] as [3 particles][xyz]
//   dr0 = r0-r1, dr1 = r1-r2, dr2 = r2-r0 ; c_k = |dr_k| - l_k -> out [B, N, 3] fp32
//
// Round 4: same as Round 3 (coalesced LDS staging) — previous bench was an
// infra failure ("container failed twice"), not a kernel verdict. One latent
// tail-path bug fixed (v.w was never loaded; dead code at this problem size).
//
// Rationale: the naive one-thread-per-molecule version is transaction-bound:
// 72 B lane stride means each 64 B line serves ~8 useful bytes per VMEM
// instruction (~0.85 TB/s effective vs 6.6 TB/s achievable). Fix: stage a
// 512-molecule tile (36 KB) into LDS with perfectly coalesced dwordx4 loads,
// do the strided record reads from LDS, stage the 12 B/molecule outputs in
// LDS and write back as coalesced dwordx4.

constexpr int F_PER_MOL = 18;                    // 9 pos + 9 vel floats
constexpr int BLOCK     = 256;
constexpr int TILE      = 512;                   // molecules per block
constexpr int IN_F4     = TILE * F_PER_MOL / 4;  // 2304 float4 = 36 KB
constexpr int OUT_F     = TILE * 3;              // 1536 floats = 6 KB
constexpr int OUT_F4    = OUT_F / 4;             // 384 float4

__global__ __launch_bounds__(BLOCK) void water_kernel(
    const float* __restrict__ x,
    const float* __restrict__ l,
    float* __restrict__ out,
    long long total_mol)
{
    __shared__ float4 sx[IN_F4];    // staged input tile (records, linear)
    __shared__ float  so[OUT_F];    // staged output tile

    const int t = threadIdx.x;
    const long long tile_base   = (long long)blockIdx.x * TILE;       // molecule idx
    const long long total_in_f  = total_mol * F_PER_MOL;              // floats
    const long long total_out_f = total_mol * 3;                      // floats

    // ---- stage in: 9 coalesced dwordx4 loads per thread -------------------
    // tile_base*72 bytes is 16B-aligned (TILE*72 = 36864 is a multiple of 16).
    const long long in_f4_base = (tile_base * F_PER_MOL) >> 2;        // float4 idx
    const float4* __restrict__ x4 = reinterpret_cast<const float4*>(x);

#pragma unroll
    for (int i = 0; i < IN_F4 / BLOCK; ++i) {                         // 9 iters
        const int s = i * BLOCK + t;
        const long long g  = in_f4_base + s;
        const long long gf = g * 4;                                   // float idx
        if (gf + 4 <= total_in_f) {
            sx[s] = x4[g];
        } else {
            // tail: partial float4 (robustness for non-multiple sizes)
            float4 v = make_float4(0.f, 0.f, 0.f, 0.f);
            if (gf + 0 < total_in_f) v.x = x[gf + 0];
            if (gf + 1 < total_in_f) v.y = x[gf + 1];
            if (gf + 2 < total_in_f) v.z = x[gf + 2];
            if (gf + 3 < total_in_f) v.w = x[gf + 3];
            sx[s] = v;
        }
    }
    __syncthreads();

    // ---- compute: 2 molecules per thread from LDS -------------------------
    // l pointer is wave-uniform -> scalar loads.
    const float l0 = l[0], l1 = l[1], l2 = l[2];
    const float* sxf = reinterpret_cast<const float*>(sx);

#pragma unroll
    for (int h = 0; h < TILE / BLOCK; ++h) {                          // 2 iters
        const int j = t + h * BLOCK;                                  // molecule in tile
        const float* m = sxf + j * F_PER_MOL;                         // 8B-aligned

        const float ox = m[0], oy = m[1], oz = m[2];
        const float ax = m[3], ay = m[4], az = m[5];
        const float bx = m[6], by = m[7], bz = m[8];

        const float d0x = ox - ax, d0y = oy - ay, d0z = oz - az;      // r0 - r1
        const float d1x = ax - bx, d1y = ay - by, d1z = az - bz;      // r1 - r2
        const float d2x = bx - ox, d2y = by - oy, d2z = bz - oz;      // r2 - r0

        const float n0 = sqrtf(d0x * d0x + d0y * d0y + d0z * d0z);
        const float n1 = sqrtf(d1x * d1x + d1y * d1y + d1z * d1z);
        const float n2 = sqrtf(d2x * d2x + d2y * d2y + d2z * d2z);

        // banks: (3j+k) mod 32, gcd(3,32)=1 -> conflict-free writes
        so[j * 3 + 0] = n0 - l0;
        so[j * 3 + 1] = n1 - l1;
        so[j * 3 + 2] = n2 - l2;
    }
    __syncthreads();

    // ---- stage out: coalesced dwordx4 stores ------------------------------
    // tile_base*12 bytes is 16B-aligned (TILE*12 = 6144 is a multiple of 16).
    const long long out_f4_base = (tile_base * 3) >> 2;               // float4 idx
    float4* __restrict__ out4 = reinterpret_cast<float4*>(out);
    const float4* so4 = reinterpret_cast<const float4*>(so);

#pragma unroll
    for (int i = 0; i < OUT_F4; i += BLOCK) {                         // i = 0, 256
        const int s = i + t;
        if (s >= OUT_F4) continue;                                    // 2nd iter: t<128
        const long long g  = out_f4_base + s;
        const long long gf = g * 4;                                   // float idx
        if (gf + 4 <= total_out_f) {
            out4[g] = so4[s];
        } else if (gf < total_out_f) {
            const float* sof = reinterpret_cast<const float*>(so);
            const int rem = (int)(total_out_f - gf);
            for (int k = 0; k < rem; ++k) out[gf + k] = sof[s * 4 + k];
        }
    }
}

extern "C" void kernel_launch(void* const* d_in, const int* in_sizes, int n_in,
                              void* d_out, int out_size, void* d_ws, size_t ws_size,
                              hipStream_t stream)
{
    const float* x = (const float*)d_in[0];   // [B*N*18] fp32
    const float* l = (const float*)d_in[1];   // [3] fp32
    float* out = (float*)d_out;               // [B*N*3] fp32

    const long long total_mol = (long long)in_sizes[0] / F_PER_MOL;   // 3,200,000
    const int grid = (int)((total_mol + TILE - 1) / TILE);            // 6250

    water_kernel<<<grid, BLOCK, 0, stream>>>(x, l, out, total_mol);
}

// Round 3
// 319.645 us; speedup vs baseline: 1.0092x; 1.0092x over previous
//
#include <hip/hip_runtime.h>

// Water constraint residuals:
//   x: [B=16, N=200000, D=18] fp32; positions = x[..., :9] as [3 particles][xyz]
//   dr0 = r0-r1, dr1 = r1-r2, dr2 = r2-r0 ; c_k = |dr_k| - l_k -> out [B, N, 3] fp32
//
// Round 5: discriminating experiment.
// Round-2 evidence: water_kernel absent from top-5 dispatches (=> < 137 us) in
// BOTH rounds, while dur_us ~ 320 us in both; top-5 is all harness poison
// fills (921.6 MB @ ~138 us, 83% HBM peak). Hypothesis: dur_us = ~275 us of
// harness fills + ~45 us kernel. This round doubles staging-phase occupancy
// (BLOCK=512, 1 mol/thread, same 42 KB LDS -> 24 waves/CU instead of 12) to
// test whether dur_us responds to kernel time at all.
//
// Kernel-side compulsory traffic: 230.4 MB read (72 B records, every 64 B
// line overlaps a position region -> velocities can't be skipped) + 38.4 MB
// write = 268.8 MB -> ~43 us floor at 6.3 TB/s.

constexpr int F_PER_MOL = 18;                    // 9 pos + 9 vel floats
constexpr int BLOCK     = 512;                   // 1 molecule per thread
constexpr int TILE      = 512;                   // molecules per block
constexpr int IN_F4     = TILE * F_PER_MOL / 4;  // 2304 float4 = 36 KB
constexpr int OUT_F     = TILE * 3;              // 1536 floats = 6 KB
constexpr int OUT_F4    = OUT_F / 4;             // 384 float4
constexpr int IN_ITERS  = (IN_F4 + BLOCK - 1) / BLOCK;  // 5 (last partial)

__global__ __launch_bounds__(BLOCK) void water_kernel(
    const float* __restrict__ x,
    const float* __restrict__ l,
    float* __restrict__ out,
    long long total_mol)
{
    __shared__ float4 sx[IN_F4];    // staged input tile (records, linear)
    __shared__ float  so[OUT_F];    // staged output tile

    const int t = threadIdx.x;
    const long long tile_base   = (long long)blockIdx.x * TILE;       // molecule idx
    const long long total_in_f  = total_mol * F_PER_MOL;              // floats
    const long long total_out_f = total_mol * 3;                      // floats

    // ---- stage in: coalesced dwordx4 loads --------------------------------
    // tile_base*72 bytes is 16B-aligned (TILE*72 = 36864 is a multiple of 16).
    const long long in_f4_base = (tile_base * F_PER_MOL) >> 2;        // float4 idx
    const float4* __restrict__ x4 = reinterpret_cast<const float4*>(x);

#pragma unroll
    for (int i = 0; i < IN_ITERS; ++i) {                              // 5 iters
        const int s = i * BLOCK + t;
        if (s < IN_F4) {
            const long long g  = in_f4_base + s;
            const long long gf = g * 4;                               // float idx
            if (gf + 4 <= total_in_f) {
                sx[s] = x4[g];
            } else {
                // tail: partial float4 (robustness for non-multiple sizes)
                float4 v = make_float4(0.f, 0.f, 0.f, 0.f);
                if (gf + 0 < total_in_f) v.x = x[gf + 0];
                if (gf + 1 < total_in_f) v.y = x[gf + 1];
                if (gf + 2 < total_in_f) v.z = x[gf + 2];
                if (gf + 3 < total_in_f) v.w = x[gf + 3];
                sx[s] = v;
            }
        }
    }
    __syncthreads();

    // ---- compute: 1 molecule per thread from LDS --------------------------
    // l pointer is wave-uniform -> scalar loads.
    const float l0 = l[0], l1 = l[1], l2 = l[2];
    const float* m = reinterpret_cast<const float*>(sx) + t * F_PER_MOL;

    const float ox = m[0], oy = m[1], oz = m[2];
    const float ax = m[3], ay = m[4], az = m[5];
    const float bx = m[6], by = m[7], bz = m[8];

    const float d0x = ox - ax, d0y = oy - ay, d0z = oz - az;          // r0 - r1
    const float d1x = ax - bx, d1y = ay - by, d1z = az - bz;          // r1 - r2
    const float d2x = bx - ox, d2y = by - oy, d2z = bz - oz;          // r2 - r0

    const float n0 = sqrtf(d0x * d0x + d0y * d0y + d0z * d0z);
    const float n1 = sqrtf(d1x * d1x + d1y * d1y + d1z * d1z);
    const float n2 = sqrtf(d2x * d2x + d2y * d2y + d2z * d2z);

    // banks: (3t+k) mod 32, gcd(3,32)=1 -> conflict-free writes
    so[t * 3 + 0] = n0 - l0;
    so[t * 3 + 1] = n1 - l1;
    so[t * 3 + 2] = n2 - l2;
    __syncthreads();

    // ---- stage out: coalesced dwordx4 stores ------------------------------
    // tile_base*12 bytes is 16B-aligned (TILE*12 = 6144 is a multiple of 16).
    if (t < OUT_F4) {
        const long long out_f4_base = (tile_base * 3) >> 2;           // float4 idx
        float4* __restrict__ out4 = reinterpret_cast<float4*>(out);
        const float4* so4 = reinterpret_cast<const float4*>(so);

        const long long g  = out_f4_base + t;
        const long long gf = g * 4;                                   // float idx
        if (gf + 4 <= total_out_f) {
            out4[g] = so4[t];
        } else if (gf < total_out_f) {
            const float* sof = reinterpret_cast<const float*>(so);
            const int rem = (int)(total_out_f - gf);
            for (int k = 0; k < rem; ++k) out[gf + k] = sof[t * 4 + k];
        }
    }
}

extern "C" void kernel_launch(void* const* d_in, const int* in_sizes, int n_in,
                              void* d_out, int out_size, void* d_ws, size_t ws_size,
                              hipStream_t stream)
{
    const float* x = (const float*)d_in[0];   // [B*N*18] fp32
    const float* l = (const float*)d_in[1];   // [3] fp32
    float* out = (float*)d_out;               // [B*N*3] fp32

    const long long total_mol = (long long)in_sizes[0] / F_PER_MOL;   // 3,200,000
    const int grid = (int)((total_mol + TILE - 1) / TILE);            // 6250

    water_kernel<<<grid, BLOCK, 0, stream>>>(x, l, out, total_mol);
}